// Round 5
// baseline (61.396 us; speedup 1.0000x reference)
//
#include <hip/hip_runtime.h>
#include <math.h>

#define NB 128
#define NR 36
#define NT 128
#define ND 1024
#define TTA 16      // tokens per scores-block
#define CK 256      // K chunk
#define LST 264     // LDS f16 row stride (528 B = 33*16 -> 16B-aligned rows)
#define WST 64      // w row stride in ws (f16), cols 36..63 = 0

typedef float    f32x4 __attribute__((ext_vector_type(4)));
typedef _Float16 f16x8 __attribute__((ext_vector_type(8)));
typedef _Float16 f16x4 __attribute__((ext_vector_type(4)));

// ============ Kernel A: cosine scores + softmax over regions -> w (f16) ============
__global__ __launch_bounds__(256, 4)
void scores_softmax(const float* __restrict__ img, const float* __restrict__ cap,
                    _Float16* __restrict__ w_ws) {
    __shared__ __align__(16) _Float16 img_c[48][LST];   // rows 36..47 never written (garbage cols ignored)
    __shared__ __align__(16) _Float16 cap_c[TTA][LST];
    __shared__ float sc_s[TTA][52];
    __shared__ float ni_s[NR];
    __shared__ float nc_s[TTA];

    const int tid  = threadIdx.x;
    const int phys = blockIdx.x;
    // XCD swizzle: XCD x owns batches [x*16, x*16+16)
    const int lb = (phys & 7) * 128 + (phys >> 3);
    const int b  = lb >> 3;
    const int t0 = (lb & 7) * TTA;

    const float* imgB = img + (size_t)b * NR * ND;
    const float* capB = cap + ((size_t)b * NT + t0) * ND;

    const int wv = tid >> 6, lane = tid & 63, ln = lane & 15, hi = lane >> 4;

    // zero the score accumulator (visible by first in-loop barrier)
    for (int i = tid; i < TTA * 52; i += 256) ((float*)sc_s)[i] = 0.f;

    float nip[9], ncp[4];
    #pragma unroll
    for (int i = 0; i < 9; ++i) nip[i] = 0.f;
    #pragma unroll
    for (int i = 0; i < 4; ++i) ncp[i] = 0.f;
    f32x4 acc[3] = {{0.f,0.f,0.f,0.f},{0.f,0.f,0.f,0.f},{0.f,0.f,0.f,0.f}};

    // prefetch chunk 0: wave wv owns img rows {4i+wv}, cap rows {4i+wv}
    float4 pimg[9], pcap[4];
    #pragma unroll
    for (int i = 0; i < 9; ++i)
        pimg[i] = *(const float4*)(imgB + (i*4 + wv)*ND + lane*4);
    #pragma unroll
    for (int i = 0; i < 4; ++i)
        pcap[i] = *(const float4*)(capB + (i*4 + wv)*ND + lane*4);

    for (int kc = 0; kc < 4; ++kc) {
        // ---- consume prefetched chunk: norms + cvt + LDS write ----
        #pragma unroll
        for (int i = 0; i < 9; ++i) {
            const float4 v = pimg[i];
            nip[i] = fmaf(v.x, v.x, fmaf(v.y, v.y, fmaf(v.z, v.z, fmaf(v.w, v.w, nip[i]))));
            f16x4 h; h[0] = (_Float16)v.x; h[1] = (_Float16)v.y;
                     h[2] = (_Float16)v.z; h[3] = (_Float16)v.w;
            *(f16x4*)(&img_c[i*4 + wv][lane*4]) = h;
        }
        #pragma unroll
        for (int i = 0; i < 4; ++i) {
            const float4 v = pcap[i];
            ncp[i] = fmaf(v.x, v.x, fmaf(v.y, v.y, fmaf(v.z, v.z, fmaf(v.w, v.w, ncp[i]))));
            f16x4 h; h[0] = (_Float16)v.x; h[1] = (_Float16)v.y;
                     h[2] = (_Float16)v.z; h[3] = (_Float16)v.w;
            *(f16x4*)(&cap_c[i*4 + wv][lane*4]) = h;
        }
        // ---- issue next chunk's loads EARLY (latency hides under barrier+MFMA) ----
        if (kc < 3) {
            const int ko = (kc + 1) * CK;
            #pragma unroll
            for (int i = 0; i < 9; ++i)
                pimg[i] = *(const float4*)(imgB + (i*4 + wv)*ND + ko + lane*4);
            #pragma unroll
            for (int i = 0; i < 4; ++i)
                pcap[i] = *(const float4*)(capB + (i*4 + wv)*ND + ko + lane*4);
        }
        __syncthreads();
        // ---- MFMA: wave wv owns K-quarter [wv*64, wv*64+64) of this chunk ----
        #pragma unroll
        for (int ks = 0; ks < 2; ++ks) {
            const int ko = wv*64 + ks*32 + hi*8;
            const f16x8 a = *(const f16x8*)(&cap_c[ln][ko]);
            #pragma unroll
            for (int nf = 0; nf < 3; ++nf) {
                const f16x8 bb = *(const f16x8*)(&img_c[nf*16 + ln][ko]);
                acc[nf] = __builtin_amdgcn_mfma_f32_16x16x32_f16(a, bb, acc[nf], 0, 0, 0);
            }
        }
        __syncthreads();
    }

    // combine K-quarters (C/D: col=lane&15 -> region, row=(lane>>4)*4+reg -> token)
    #pragma unroll
    for (int nf = 0; nf < 3; ++nf)
        #pragma unroll
        for (int j = 0; j < 4; ++j)
            atomicAdd(&sc_s[hi*4 + j][nf*16 + ln], acc[nf][j]);

    // norms: wave wv exclusively owns its rows; butterfly reduce
    #pragma unroll
    for (int i = 0; i < 9; ++i) {
        float s = nip[i];
        #pragma unroll
        for (int off = 32; off; off >>= 1) s += __shfl_xor(s, off, 64);
        if (lane == 0) ni_s[i*4 + wv] = sqrtf(s);
    }
    #pragma unroll
    for (int i = 0; i < 4; ++i) {
        float s = ncp[i];
        #pragma unroll
        for (int off = 32; off; off >>= 1) s += __shfl_xor(s, off, 64);
        if (lane == 0) nc_s[i*4 + wv] = sqrtf(s);
    }
    __syncthreads();

    // softmax over regions, one thread per token; write w (f16, cols 36..63 = 0)
    if (tid < TTA) {
        const float nct = nc_s[tid];
        float v[NR];
        float m = -1e30f;
        #pragma unroll
        for (int r = 0; r < NR; ++r) {
            const float d = fmaxf(ni_s[r] * nct, 1e-8f);
            v[r] = sc_s[tid][r] / d;
            m = fmaxf(m, v[r]);
        }
        float sum = 0.f;
        #pragma unroll
        for (int r = 0; r < NR; ++r) { v[r] = __expf(v[r] - m); sum += v[r]; }
        const float inv = 1.f / sum;
        _Float16* wO = w_ws + (size_t)(b * NT + t0 + tid) * WST;
        #pragma unroll
        for (int q = 0; q < 8; ++q) {
            f16x8 h;
            #pragma unroll
            for (int j = 0; j < 8; ++j) {
                const int r = q * 8 + j;
                h[j] = (r < NR) ? (_Float16)(v[r] * inv) : (_Float16)0.f;
            }
            *(f16x8*)(wO + q * 8) = h;
        }
    }
}

// ============ Kernel B: out[t][d] = sum_r w[t][r] * img[r][d] via MFMA ============
__global__ __launch_bounds__(256, 4)
void pool_mfma(const float* __restrict__ img, const _Float16* __restrict__ w_ws,
               float* __restrict__ out) {
    const int tid  = threadIdx.x;
    const int phys = blockIdx.x;
    const int lb = (phys & 7) * 256 + (phys >> 3);   // same XCD->batch mapping as kernel A
    const int b  = lb >> 4;
    const int tq = (lb >> 2) & 3;
    const int dq = lb & 3;
    const int t0 = tq * 32;

    const int wv = tid >> 6, lane = tid & 63, ln = lane & 15, hi = lane >> 4;
    const int dw = dq * 256 + wv * 64;               // this wave's d-base (64 wide)

    const float*    imgB = img  + (size_t)b * NR * ND;
    const _Float16* wB   = w_ws + (size_t)(b * NT + t0) * WST;
    float*          outB = out  + ((size_t)(b * NT + t0)) * ND;

    // A-frags (w): A[m=t][k=r]; lane: m = mfrag*16+ln, k = kk*32 + hi*8 + j
    f16x8 afr[2][2];
    #pragma unroll
    for (int mfr = 0; mfr < 2; ++mfr)
        #pragma unroll
        for (int kk = 0; kk < 2; ++kk)
            afr[mfr][kk] = *(const f16x8*)(wB + (mfr * 16 + ln) * WST + kk * 32 + hi * 8);

    f32x4 acc[2][4];
    #pragma unroll
    for (int mfr = 0; mfr < 2; ++mfr)
        #pragma unroll
        for (int nf = 0; nf < 4; ++nf)
            acc[mfr][nf] = (f32x4){0.f, 0.f, 0.f, 0.f};

    #pragma unroll
    for (int nf = 0; nf < 4; ++nf) {
        const int dcol = dw + nf * 16 + ln;
        #pragma unroll
        for (int kk = 0; kk < 2; ++kk) {
            // B-frag (img): B[k=r][n=d]; r >= 36 clamped (w cols are zero there)
            f16x8 bfr;
            #pragma unroll
            for (int j = 0; j < 8; ++j) {
                int r = kk * 32 + hi * 8 + j;
                if (r >= NR) r = NR - 1;             // safe addr; killed by w==0
                bfr[j] = (_Float16)imgB[r * ND + dcol];
            }
            #pragma unroll
            for (int mfr = 0; mfr < 2; ++mfr)
                acc[mfr][nf] = __builtin_amdgcn_mfma_f32_16x16x32_f16(afr[mfr][kk], bfr, acc[mfr][nf], 0, 0, 0);
        }
    }

    // store: D row = mfr*16 + hi*4 + j (token), col = nf*16 + ln (d)
    #pragma unroll
    for (int mfr = 0; mfr < 2; ++mfr)
        #pragma unroll
        for (int nf = 0; nf < 4; ++nf)
            #pragma unroll
            for (int j = 0; j < 4; ++j)
                outB[(size_t)(mfr * 16 + hi * 4 + j) * ND + dw + nf * 16 + ln] = acc[mfr][nf][j];
}

extern "C" void kernel_launch(void* const* d_in, const int* in_sizes, int n_in,
                              void* d_out, int out_size, void* d_ws, size_t ws_size,
                              hipStream_t stream) {
    const float* img = (const float*)d_in[0];   // [B, R, D]
    const float* cap = (const float*)d_in[1];   // [B, T, D]
    float* out = (float*)d_out;                 // [B, T, D]
    _Float16* w_ws = (_Float16*)d_ws;           // [B, T, 64] f16 = 2.0 MB

    scores_softmax<<<NB * 8, 256, 0, stream>>>(img, cap, w_ws);
    pool_mfma<<<NB * 16, 256, 0, stream>>>(img, w_ws, out);
}

// Round 6
// 44.418 us; speedup vs baseline: 1.3822x; 1.3822x over previous
//
#include <hip/hip_runtime.h>
#include <math.h>

#define NB 128
#define NR 36
#define NT 128
#define ND 1024
#define TTA 32      // tokens per scores-block
#define IST 1032    // img_c f16 row stride (2064 B = 129*16: 16B-aligned rows, 2-way banks)
#define WST 64      // w row stride in ws (f16), cols 36..63 = 0

typedef float    f32x4 __attribute__((ext_vector_type(4)));
typedef _Float16 f16x8 __attribute__((ext_vector_type(8)));
typedef _Float16 f16x4 __attribute__((ext_vector_type(4)));

// ============ Kernel A: cosine scores + softmax over regions -> w (f16) ============
// Structure: stage img once (1 barrier) -> barrier-free K-loop (cap global->reg
// A-frags, img LDS B-frags, MFMA) -> atomic combine (1 barrier) -> softmax.
__global__ __launch_bounds__(256, 2)
void scores_softmax(const float* __restrict__ img, const float* __restrict__ cap,
                    _Float16* __restrict__ w_ws) {
    __shared__ __align__(16) _Float16 img_c[NR][IST];   // 74304 B
    __shared__ float sc_s[TTA][49];                     //  6272 B
    __shared__ float ni_s[NR];                          //   144 B
    __shared__ float nc_s[TTA];                         //   128 B  (raw sum-sq)

    const int tid  = threadIdx.x;
    const int phys = blockIdx.x;
    // XCD swizzle: XCD x owns batches [x*16, x*16+16) (matches kernel B)
    const int lb = (phys & 7) * 64 + (phys >> 3);
    const int b  = lb >> 2;
    const int t0 = (lb & 3) * TTA;

    const float* imgB = img + (size_t)b * NR * ND;
    const float* capB = cap + ((size_t)b * NT + t0) * ND;

    const int wv = tid >> 6, lane = tid & 63, ln = lane & 15, hi = lane >> 4;

    // zero reduction targets (visible at barrier 1)
    for (int i = tid; i < TTA * 49; i += 256) ((float*)sc_s)[i] = 0.f;
    if (tid < TTA) nc_s[tid] = 0.f;

    // ---- stage img f32 -> f16 once; wave wv exclusively owns rows [9wv, 9wv+9) ----
    float nip[9];
    #pragma unroll
    for (int i = 0; i < 9; ++i) nip[i] = 0.f;
    #pragma unroll
    for (int j = 0; j < 36; ++j) {
        const int row = wv * 9 + (j >> 2);
        const int c4  = (j & 3) * 64 + lane;            // float4 column group
        const float4 v = *(const float4*)(imgB + row * ND + c4 * 4);
        nip[j >> 2] = fmaf(v.x, v.x, fmaf(v.y, v.y, fmaf(v.z, v.z, fmaf(v.w, v.w, nip[j >> 2]))));
        f16x4 h; h[0] = (_Float16)v.x; h[1] = (_Float16)v.y;
                 h[2] = (_Float16)v.z; h[3] = (_Float16)v.w;
        *(f16x4*)(&img_c[row][c4 * 4]) = h;
    }
    #pragma unroll
    for (int jr = 0; jr < 9; ++jr) {
        float s = nip[jr];
        #pragma unroll
        for (int off = 32; off; off >>= 1) s += __shfl_xor(s, off, 64);
        if (lane == 0) ni_s[wv * 9 + jr] = sqrtf(s);
    }
    __syncthreads();   // barrier 1: img_c, ni_s, zero-init visible

    // ---- barrier-free K-loop ----
    // wave: token-half th = (wv&1)*16, K-half kbase = (wv>>1)*512
    const int th    = (wv & 1) * 16;
    const int kbase = (wv >> 1) * 512;

    // loop-invariant row pointers
    const float* capR = capB + (size_t)(th + ln) * ND + kbase + hi * 8;  // A source (f32)
    const char*  bp0  = (const char*)&img_c[ln][0];                      // regions  0..15
    const char*  bp1  = (const char*)&img_c[16 + ln][0];                 // regions 16..31
    const char*  bp2  = (const char*)&img_c[32 + (ln < 4 ? ln : 3)][0];  // regions 32..35 (ln>=4 clamped, masked later)

    f32x4 acc0 = {0.f,0.f,0.f,0.f}, acc1 = acc0, acc2 = acc0;
    float ncp = 0.f;

    #pragma unroll
    for (int step = 0; step < 16; ++step) {
        const float4 u0 = *(const float4*)(capR + step * 32);
        const float4 u1 = *(const float4*)(capR + step * 32 + 4);
        ncp = fmaf(u0.x,u0.x, fmaf(u0.y,u0.y, fmaf(u0.z,u0.z, fmaf(u0.w,u0.w, ncp))));
        ncp = fmaf(u1.x,u1.x, fmaf(u1.y,u1.y, fmaf(u1.z,u1.z, fmaf(u1.w,u1.w, ncp))));
        f16x8 a;
        a[0] = (_Float16)u0.x; a[1] = (_Float16)u0.y; a[2] = (_Float16)u0.z; a[3] = (_Float16)u0.w;
        a[4] = (_Float16)u1.x; a[5] = (_Float16)u1.y; a[6] = (_Float16)u1.z; a[7] = (_Float16)u1.w;
        const int koff2 = (kbase + step * 32 + hi * 8) * 2;   // byte offset within row
        const f16x8 b0 = *(const f16x8*)(bp0 + koff2);
        const f16x8 b1 = *(const f16x8*)(bp1 + koff2);
        const f16x8 b2 = *(const f16x8*)(bp2 + koff2);
        acc0 = __builtin_amdgcn_mfma_f32_16x16x32_f16(a, b0, acc0, 0, 0, 0);
        acc1 = __builtin_amdgcn_mfma_f32_16x16x32_f16(a, b1, acc1, 0, 0, 0);
        acc2 = __builtin_amdgcn_mfma_f32_16x16x32_f16(a, b2, acc2, 0, 0, 0);
    }

    // ---- combine K-halves (C/D: col=ln -> region, row=hi*4+j -> token) ----
    #pragma unroll
    for (int j = 0; j < 4; ++j) {
        atomicAdd(&sc_s[th + hi*4 + j][ln],      acc0[j]);
        atomicAdd(&sc_s[th + hi*4 + j][16 + ln], acc1[j]);
        atomicAdd(&sc_s[th + hi*4 + j][32 + ln], acc2[j]);
    }
    // cap norm: lanes {ln, ln+16, ln+32, ln+48} hold k-partials for token th+ln
    {
        float s = ncp;
        s += __shfl_xor(s, 16, 64);
        s += __shfl_xor(s, 32, 64);
        if (lane < 16) atomicAdd(&nc_s[th + ln], s);
    }
    __syncthreads();   // barrier 2: sc_s, nc_s complete

    // ---- softmax over regions, one thread per token; write w (f16, cols 36..63 = 0) ----
    if (tid < TTA) {
        const float nct = sqrtf(nc_s[tid]);
        float v[NR];
        float m = -1e30f;
        #pragma unroll
        for (int r = 0; r < NR; ++r) {
            const float d = fmaxf(ni_s[r] * nct, 1e-8f);
            v[r] = sc_s[tid][r] / d;
            m = fmaxf(m, v[r]);
        }
        float sum = 0.f;
        #pragma unroll
        for (int r = 0; r < NR; ++r) { v[r] = __expf(v[r] - m); sum += v[r]; }
        const float inv = 1.f / sum;
        _Float16* wO = w_ws + (size_t)(b * NT + t0 + tid) * WST;
        #pragma unroll
        for (int q = 0; q < 8; ++q) {
            f16x8 h;
            #pragma unroll
            for (int j = 0; j < 8; ++j) {
                const int r = q * 8 + j;
                h[j] = (r < NR) ? (_Float16)(v[r] * inv) : (_Float16)0.f;
            }
            *(f16x8*)(wO + q * 8) = h;
        }
    }
}

// ============ Kernel B: out[t][d] = sum_r w[t][r] * img[r][d] via MFMA ============
__global__ __launch_bounds__(256, 4)
void pool_mfma(const float* __restrict__ img, const _Float16* __restrict__ w_ws,
               float* __restrict__ out) {
    const int tid  = threadIdx.x;
    const int phys = blockIdx.x;
    const int lb = (phys & 7) * 256 + (phys >> 3);   // same XCD->batch mapping as kernel A
    const int b  = lb >> 4;
    const int tq = (lb >> 2) & 3;
    const int dq = lb & 3;
    const int t0 = tq * 32;

    const int wv = tid >> 6, lane = tid & 63, ln = lane & 15, hi = lane >> 4;
    const int dw = dq * 256 + wv * 64;               // this wave's d-base (64 wide)

    const float*    imgB = img  + (size_t)b * NR * ND;
    const _Float16* wB   = w_ws + (size_t)(b * NT + t0) * WST;
    float*          outB = out  + ((size_t)(b * NT + t0)) * ND;

    // A-frags (w): A[m=t][k=r]; lane: m = mfrag*16+ln, k = kk*32 + hi*8 + j
    f16x8 afr[2][2];
    #pragma unroll
    for (int mfr = 0; mfr < 2; ++mfr)
        #pragma unroll
        for (int kk = 0; kk < 2; ++kk)
            afr[mfr][kk] = *(const f16x8*)(wB + (mfr * 16 + ln) * WST + kk * 32 + hi * 8);

    f32x4 acc[2][4];
    #pragma unroll
    for (int mfr = 0; mfr < 2; ++mfr)
        #pragma unroll
        for (int nf = 0; nf < 4; ++nf)
            acc[mfr][nf] = (f32x4){0.f, 0.f, 0.f, 0.f};

    #pragma unroll
    for (int nf = 0; nf < 4; ++nf) {
        const int dcol = dw + nf * 16 + ln;
        #pragma unroll
        for (int kk = 0; kk < 2; ++kk) {
            // B-frag (img): B[k=r][n=d]; r >= 36 clamped (w cols are zero there)
            f16x8 bfr;
            #pragma unroll
            for (int j = 0; j < 8; ++j) {
                int r = kk * 32 + hi * 8 + j;
                if (r >= NR) r = NR - 1;             // safe addr; killed by w==0
                bfr[j] = (_Float16)imgB[r * ND + dcol];
            }
            #pragma unroll
            for (int mfr = 0; mfr < 2; ++mfr)
                acc[mfr][nf] = __builtin_amdgcn_mfma_f32_16x16x32_f16(afr[mfr][kk], bfr, acc[mfr][nf], 0, 0, 0);
        }
    }

    // store: D row = mfr*16 + hi*4 + j (token), col = nf*16 + ln (d)
    #pragma unroll
    for (int mfr = 0; mfr < 2; ++mfr)
        #pragma unroll
        for (int nf = 0; nf < 4; ++nf)
            #pragma unroll
            for (int j = 0; j < 4; ++j)
                outB[(size_t)(mfr * 16 + hi * 4 + j) * ND + dw + nf * 16 + ln] = acc[mfr][nf][j];
}

extern "C" void kernel_launch(void* const* d_in, const int* in_sizes, int n_in,
                              void* d_out, int out_size, void* d_ws, size_t ws_size,
                              hipStream_t stream) {
    const float* img = (const float*)d_in[0];   // [B, R, D]
    const float* cap = (const float*)d_in[1];   // [B, T, D]
    float* out = (float*)d_out;                 // [B, T, D]
    _Float16* w_ws = (_Float16*)d_ws;           // [B, T, 64] f16 = 2.0 MB

    scores_softmax<<<NB * 4, 256, 0, stream>>>(img, cap, w_ws);
    pool_mfma<<<NB * 16, 256, 0, stream>>>(img, w_ws, out);
}